// Round 7
// baseline (834.189 us; speedup 1.0000x reference)
//
#include <hip/hip_runtime.h>

#define Bdim 64
#define Tdim 512
#define Idim 512
#define Hdim 512
#define CLIPV 10.0f
#define NREGP 46        // k-pairs per thread in arch VGPRs (184 dwords)
#define NLDSP 18        // k-pairs per thread in LDS (144 KB)

typedef __attribute__((ext_vector_type(4))) float f32x4;
typedef __attribute__((ext_vector_type(8))) short bf16x8;
typedef _Float16 half2v __attribute__((ext_vector_type(2)));

__device__ __forceinline__ ushort f2bf(float f) {
    unsigned u = __builtin_bit_cast(unsigned, f);
    u += 0x7fffu + ((u >> 16) & 1u);   // round-to-nearest-even
    return (ushort)(u >> 16);
}
__device__ __forceinline__ float bf2f(ushort h) {
    return __builtin_bit_cast(float, (unsigned)h << 16);
}
__device__ __forceinline__ void split_bf(float f, ushort& h, ushort& l) {
    h = f2bf(f);
    l = f2bf(f - bf2f(h));
}
__device__ __forceinline__ float dot2acc(uint r, uint h2, float acc) {
#if __has_builtin(__builtin_amdgcn_fdot2)
    return __builtin_amdgcn_fdot2(__builtin_bit_cast(half2v, r),
                                  __builtin_bit_cast(half2v, h2), acc, false);
#else
    half2v a = __builtin_bit_cast(half2v, r);
    half2v b = __builtin_bit_cast(half2v, h2);
    return acc + (float)a.x * (float)b.x + (float)a.y * (float)b.y;
#endif
}
__device__ __forceinline__ uint packf16(float a, float b) {
    _Float16 fa = (_Float16)a, fb = (_Float16)b;
    return (uint)__builtin_bit_cast(ushort, fa) |
           ((uint)__builtin_bit_cast(ushort, fb) << 16);
}
__device__ __forceinline__ ushort f2h(float f) {
    _Float16 h = (_Float16)f;
    return __builtin_bit_cast(ushort, h);
}
__device__ __forceinline__ float fastrcp(float x) {
#if __has_builtin(__builtin_amdgcn_rcpf)
    return __builtin_amdgcn_rcpf(x);
#else
    return 1.0f / x;
#endif
}

// ---- cast + transpose W into hi/lo bf16 (feed-forward GEMM operands) ----
__global__ __launch_bounds__(256) void transpose_w_kernel(const float* __restrict__ w,
                                                          ushort* __restrict__ wth,
                                                          ushort* __restrict__ wtl) {
    int idx = blockIdx.x * 256 + threadIdx.x;
    int k = idx >> 9, n = idx & 511;
    ushort h, l;
    split_bf(w[idx], h, l);
    wth[n * Idim + k] = h;
    wtl[n * Idim + k] = l;
}

// ---- pack R into fp16 pairs, layout d = i*2048 + t*4 + q ----
// thread t covers k-quarter (t>>7) and cols (t&127)*4+q; pair i -> k = kq*128+2i
__global__ __launch_bounds__(256) void pack_r_kernel(const float* __restrict__ Rw,
                                                     uint* __restrict__ rpk) {
    int d = blockIdx.x * 256 + threadIdx.x;      // 0..131071
    int i = d >> 11;
    int rem = d & 2047;
    int t = rem >> 2, q = rem & 3;
    int k = (t >> 7) * 128 + 2 * i;
    int c = ((t & 127) << 2) + q;
    rpk[d] = packf16(Rw[(size_t)k * Hdim + c], Rw[(size_t)(k + 1) * Hdim + c]);
}

// ---- phase 1: pre = x @ W + bias via bf16x3 MFMA ----
#define BM 128
#define BN 128
#define BK 32
__global__ __launch_bounds__(256) void gemm_xw(
    const float* __restrict__ A,
    const ushort* __restrict__ Bth,
    const ushort* __restrict__ Btl,
    const float* __restrict__ bias,
    float* __restrict__ C,
    int M, int N, int K)
{
    __shared__ ushort AsH[BM][BK];
    __shared__ ushort AsL[BM][BK];
    __shared__ ushort BsH[BN][BK];
    __shared__ ushort BsL[BN][BK];
    int bm = blockIdx.x, bn = blockIdx.y;
    int tid = threadIdx.x;
    int wave = tid >> 6, lane = tid & 63;
    int wr = wave >> 1, wc = wave & 1;
    f32x4 acc[4][4] = {};
    const int row0 = bm * BM, col0 = bn * BN;
    const int sr = tid >> 1;
    const int sc = (tid & 1) * 16;

    for (int kt = 0; kt < K; kt += BK) {
        const float* gA = A + (size_t)(row0 + sr) * K + kt + sc;
        #pragma unroll
        for (int q = 0; q < 4; ++q) {
            float4 v = *(const float4*)(gA + q * 4);
            ushort4 h4, l4;
            split_bf(v.x, h4.x, l4.x);
            split_bf(v.y, h4.y, l4.y);
            split_bf(v.z, h4.z, l4.z);
            split_bf(v.w, h4.w, l4.w);
            *(ushort4*)&AsH[sr][sc + q * 4] = h4;
            *(ushort4*)&AsL[sr][sc + q * 4] = l4;
        }
        const int4* gBh = (const int4*)(Bth + (size_t)(col0 + sr) * K + kt + sc);
        *(int4*)&BsH[sr][sc]     = gBh[0];
        *(int4*)&BsH[sr][sc + 8] = gBh[1];
        const int4* gBl = (const int4*)(Btl + (size_t)(col0 + sr) * K + kt + sc);
        *(int4*)&BsL[sr][sc]     = gBl[0];
        *(int4*)&BsL[sr][sc + 8] = gBl[1];
        __syncthreads();

        const int r = lane & 15, kg = lane >> 4;
        bf16x8 ah[4], al[4], bh[4], bl[4];
        #pragma unroll
        for (int m = 0; m < 4; ++m) {
            ah[m] = *(const bf16x8*)&AsH[wr * 64 + m * 16 + r][kg * 8];
            al[m] = *(const bf16x8*)&AsL[wr * 64 + m * 16 + r][kg * 8];
        }
        #pragma unroll
        for (int n = 0; n < 4; ++n) {
            bh[n] = *(const bf16x8*)&BsH[wc * 64 + n * 16 + r][kg * 8];
            bl[n] = *(const bf16x8*)&BsL[wc * 64 + n * 16 + r][kg * 8];
        }
        #pragma unroll
        for (int m = 0; m < 4; ++m)
            #pragma unroll
            for (int n = 0; n < 4; ++n) {
                acc[m][n] = __builtin_amdgcn_mfma_f32_16x16x32_bf16(ah[m], bh[n], acc[m][n], 0, 0, 0);
                acc[m][n] = __builtin_amdgcn_mfma_f32_16x16x32_bf16(ah[m], bl[n], acc[m][n], 0, 0, 0);
                acc[m][n] = __builtin_amdgcn_mfma_f32_16x16x32_bf16(al[m], bh[n], acc[m][n], 0, 0, 0);
            }
        __syncthreads();
    }

    const int cl = lane & 15, rg = lane >> 4;
    #pragma unroll
    for (int n = 0; n < 4; ++n) {
        int gc = col0 + wc * 64 + n * 16 + cl;
        float bv = bias[gc];
        #pragma unroll
        for (int m = 0; m < 4; ++m) {
            int gr = row0 + wr * 64 + m * 16 + rg * 4;
            #pragma unroll
            for (int r2 = 0; r2 < 4; ++r2)
                C[(size_t)(gr + r2) * N + gc] = acc[m][n][r2] + bv;
        }
    }
}

// ---- phase 2: recurrence. 64 WGs (1 row each), 512 threads, zero cross-WG sync.
// R (fp16) CU-resident: 184 dwords/thread in arch VGPRs + 144 KB in LDS.
// h broadcast via one b32 LDS read/lane + readlane into the dot2 SGPR operand.
__global__ __launch_bounds__(512, 2) void rnn_reg_kernel(
    const uint* __restrict__ Rpk,    // [131072] packed fp16 pairs
    float* __restrict__ out,         // [B][T][H]: pre -> h in place
    float* __restrict__ hlast,       // [B][H]
    const float* __restrict__ h0)    // [B][H]
{
    __shared__ uint Rlds[NLDSP * 2048];   // 144 KB
    __shared__ ushort h1[Hdim];           // 1 KB, fp16 h_{t-1}
    __shared__ float part[4][Hdim];       // 8 KB, k-quarter partials

    const int tid  = threadIdx.x;
    const int row  = blockIdx.x;
    const int kq   = tid >> 7;            // k-quarter (uniform per wave)
    const int lane = tid & 63;
    const int c0   = (tid & 127) * 4;     // 4 output columns (dot phase)
    const int hb   = kq * 64;             // uint-pair base of this wave's quarter

    // register-resident R: 46 x uint4 = 184 dwords (arch VGPRs)
    uint4 rr4[NREGP];
    const uint* rbase = Rpk + tid * 4;
    #pragma unroll
    for (int i = 0; i < NREGP; ++i)
        rr4[i] = *(const uint4*)(rbase + i * 2048);
    // LDS-resident R: 18 x uint4 per thread, lane-consecutive layout
    #pragma unroll
    for (int ip = 0; ip < NLDSP; ++ip)
        *(uint4*)&Rlds[ip * 2048 + tid * 4] =
            *(const uint4*)(rbase + (NREGP + ip) * 2048);

    h1[tid] = f2h(h0[row * Hdim + tid]);
    __syncthreads();

    float* orow = out + (size_t)row * Tdim * Hdim;

    for (int t = 0; t < Tdim; ++t, orow += Hdim) {
        float pre = orow[tid];                        // issued early, used in finalize
        uint hval = ((const uint*)h1)[hb + lane];     // lane's h pair; 1 b32, conflict-free

        float a0 = 0.f, a1 = 0.f, a2 = 0.f, a3 = 0.f;
        // LDS part first (longer latency), pairs NREGP..63
        #pragma unroll
        for (int i = 0; i < NLDSP; ++i) {
            uint hvi = __builtin_amdgcn_readlane(hval, NREGP + i);
            uint4 rv = *(const uint4*)&Rlds[i * 2048 + tid * 4];
            a0 = dot2acc(rv.x, hvi, a0);
            a1 = dot2acc(rv.y, hvi, a1);
            a2 = dot2acc(rv.z, hvi, a2);
            a3 = dot2acc(rv.w, hvi, a3);
        }
        // register part: pairs 0..NREGP-1, h via readlane broadcast (SGPR operand)
        #pragma unroll
        for (int i = 0; i < NREGP; ++i) {
            uint hvi = __builtin_amdgcn_readlane(hval, i);
            uint4 rv = rr4[i];
            a0 = dot2acc(rv.x, hvi, a0);
            a1 = dot2acc(rv.y, hvi, a1);
            a2 = dot2acc(rv.z, hvi, a2);
            a3 = dot2acc(rv.w, hvi, a3);
        }
        *(f32x4*)&part[kq][c0] = (f32x4){a0, a1, a2, a3};
        __syncthreads();

        // finalize: all 512 threads, one column each
        float s = part[0][tid] + part[1][tid] + part[2][tid] + part[3][tid] + pre;
        s = fminf(fmaxf(s, -CLIPV), CLIPV);
        float e = __expf(2.0f * s);                   // v_exp_f32
        float v = (e - 1.0f) * fastrcp(e + 1.0f);     // tanh(s)
        orow[tid] = v;
        h1[tid] = f2h(v);
        if (t == Tdim - 1) hlast[row * Hdim + tid] = v;
        __syncthreads();
    }
}

extern "C" void kernel_launch(void* const* d_in, const int* in_sizes, int n_in,
                              void* d_out, int out_size, void* d_ws, size_t ws_size,
                              hipStream_t stream) {
    const float* x    = (const float*)d_in[0];
    const float* W    = (const float*)d_in[1];
    const float* R    = (const float*)d_in[2];
    const float* bias = (const float*)d_in[3];
    const float* h0   = (const float*)d_in[4];
    float* out = (float*)d_out;

    ushort* wth = (ushort*)d_ws;                                // 512 KB
    ushort* wtl = wth + (size_t)Idim * Hdim;                    // 512 KB
    uint* rpk   = (uint*)((char*)d_ws + (1u << 20));            // 512 KB

    transpose_w_kernel<<<(Idim * Hdim + 255) / 256, 256, 0, stream>>>(W, wth, wtl);
    pack_r_kernel<<<512, 256, 0, stream>>>(R, rpk);

    dim3 gg(Bdim * Tdim / BM, Hdim / BN);
    gemm_xw<<<gg, 256, 0, stream>>>(x, wth, wtl, bias, out, Bdim * Tdim, Hdim, Idim);

    rnn_reg_kernel<<<Bdim, 512, 0, stream>>>(
        rpk, out, out + (size_t)Bdim * Tdim * Hdim, h0);
}

// Round 8
// 780.863 us; speedup vs baseline: 1.0683x; 1.0683x over previous
//
#include <hip/hip_runtime.h>

#define Bdim 64
#define Tdim 512
#define Idim 512
#define Hdim 512
#define CLIPV 10.0f
#define NREGG 50        // reg-resident groups of 4 dwords (200 dwords/thread)
#define NLDSG 14        // LDS-resident groups (112 KB)

typedef __attribute__((ext_vector_type(4))) float f32x4;
typedef __attribute__((ext_vector_type(8))) short bf16x8;
typedef _Float16 half2v __attribute__((ext_vector_type(2)));

__device__ __forceinline__ ushort f2bf(float f) {
    unsigned u = __builtin_bit_cast(unsigned, f);
    u += 0x7fffu + ((u >> 16) & 1u);   // round-to-nearest-even
    return (ushort)(u >> 16);
}
__device__ __forceinline__ float bf2f(ushort h) {
    return __builtin_bit_cast(float, (unsigned)h << 16);
}
__device__ __forceinline__ void split_bf(float f, ushort& h, ushort& l) {
    h = f2bf(f);
    l = f2bf(f - bf2f(h));
}
__device__ __forceinline__ float dot2acc(uint r, uint h2, float acc) {
#if __has_builtin(__builtin_amdgcn_fdot2)
    return __builtin_amdgcn_fdot2(__builtin_bit_cast(half2v, r),
                                  __builtin_bit_cast(half2v, h2), acc, false);
#else
    half2v a = __builtin_bit_cast(half2v, r);
    half2v b = __builtin_bit_cast(half2v, h2);
    return acc + (float)a.x * (float)b.x + (float)a.y * (float)b.y;
#endif
}
__device__ __forceinline__ uint packf16(float a, float b) {
    _Float16 fa = (_Float16)a, fb = (_Float16)b;
    return (uint)__builtin_bit_cast(ushort, fa) |
           ((uint)__builtin_bit_cast(ushort, fb) << 16);
}
__device__ __forceinline__ ushort f2h(float f) {
    _Float16 h = (_Float16)f;
    return __builtin_bit_cast(ushort, h);
}
__device__ __forceinline__ float fastrcp(float x) {
#if __has_builtin(__builtin_amdgcn_rcpf)
    return __builtin_amdgcn_rcpf(x);
#else
    return 1.0f / x;
#endif
}

// ---- cast + transpose W into hi/lo bf16 (feed-forward GEMM operands) ----
__global__ __launch_bounds__(256) void transpose_w_kernel(const float* __restrict__ w,
                                                          ushort* __restrict__ wth,
                                                          ushort* __restrict__ wtl) {
    int idx = blockIdx.x * 256 + threadIdx.x;
    int k = idx >> 9, n = idx & 511;
    ushort h, l;
    split_bf(w[idx], h, l);
    wth[n * Idim + k] = h;
    wtl[n * Idim + k] = l;
}

// ---- pack R (fp16 pairs) for the k-eighth-per-wave recurrence layout ----
// d = g*2048 + t*4 + r ; j = g>>1 (chunk), half = g&1
// consuming thread t = (w,l): kp = w*32 + j ; col = l*8 + half*4 + r
// rpk[d] = pack(R[2kp][col], R[2kp+1][col])
__global__ __launch_bounds__(256) void pack_r_kernel(const float* __restrict__ Rw,
                                                     uint* __restrict__ rpk) {
    int d = blockIdx.x * 256 + threadIdx.x;      // 0..131071
    int g = d >> 11;
    int rem = d & 2047;
    int t = rem >> 2, r = rem & 3;
    int j = g >> 1, half = g & 1;
    int kp = (t >> 6) * 32 + j;
    int c  = (t & 63) * 8 + half * 4 + r;
    rpk[d] = packf16(Rw[(size_t)(2 * kp) * Hdim + c],
                     Rw[(size_t)(2 * kp + 1) * Hdim + c]);
}

// ---- phase 1: pre = x @ W + bias via bf16x3 MFMA ----
#define BM 128
#define BN 128
#define BK 32
__global__ __launch_bounds__(256) void gemm_xw(
    const float* __restrict__ A,
    const ushort* __restrict__ Bth,
    const ushort* __restrict__ Btl,
    const float* __restrict__ bias,
    float* __restrict__ C,
    int M, int N, int K)
{
    __shared__ ushort AsH[BM][BK];
    __shared__ ushort AsL[BM][BK];
    __shared__ ushort BsH[BN][BK];
    __shared__ ushort BsL[BN][BK];
    int bm = blockIdx.x, bn = blockIdx.y;
    int tid = threadIdx.x;
    int wave = tid >> 6, lane = tid & 63;
    int wr = wave >> 1, wc = wave & 1;
    f32x4 acc[4][4] = {};
    const int row0 = bm * BM, col0 = bn * BN;
    const int sr = tid >> 1;
    const int sc = (tid & 1) * 16;

    for (int kt = 0; kt < K; kt += BK) {
        const float* gA = A + (size_t)(row0 + sr) * K + kt + sc;
        #pragma unroll
        for (int q = 0; q < 4; ++q) {
            float4 v = *(const float4*)(gA + q * 4);
            ushort4 h4, l4;
            split_bf(v.x, h4.x, l4.x);
            split_bf(v.y, h4.y, l4.y);
            split_bf(v.z, h4.z, l4.z);
            split_bf(v.w, h4.w, l4.w);
            *(ushort4*)&AsH[sr][sc + q * 4] = h4;
            *(ushort4*)&AsL[sr][sc + q * 4] = l4;
        }
        const int4* gBh = (const int4*)(Bth + (size_t)(col0 + sr) * K + kt + sc);
        *(int4*)&BsH[sr][sc]     = gBh[0];
        *(int4*)&BsH[sr][sc + 8] = gBh[1];
        const int4* gBl = (const int4*)(Btl + (size_t)(col0 + sr) * K + kt + sc);
        *(int4*)&BsL[sr][sc]     = gBl[0];
        *(int4*)&BsL[sr][sc + 8] = gBl[1];
        __syncthreads();

        const int r = lane & 15, kg = lane >> 4;
        bf16x8 ah[4], al[4], bh[4], bl[4];
        #pragma unroll
        for (int m = 0; m < 4; ++m) {
            ah[m] = *(const bf16x8*)&AsH[wr * 64 + m * 16 + r][kg * 8];
            al[m] = *(const bf16x8*)&AsL[wr * 64 + m * 16 + r][kg * 8];
        }
        #pragma unroll
        for (int n = 0; n < 4; ++n) {
            bh[n] = *(const bf16x8*)&BsH[wc * 64 + n * 16 + r][kg * 8];
            bl[n] = *(const bf16x8*)&BsL[wc * 64 + n * 16 + r][kg * 8];
        }
        #pragma unroll
        for (int m = 0; m < 4; ++m)
            #pragma unroll
            for (int n = 0; n < 4; ++n) {
                acc[m][n] = __builtin_amdgcn_mfma_f32_16x16x32_bf16(ah[m], bh[n], acc[m][n], 0, 0, 0);
                acc[m][n] = __builtin_amdgcn_mfma_f32_16x16x32_bf16(ah[m], bl[n], acc[m][n], 0, 0, 0);
                acc[m][n] = __builtin_amdgcn_mfma_f32_16x16x32_bf16(al[m], bh[n], acc[m][n], 0, 0, 0);
            }
        __syncthreads();
    }

    const int cl = lane & 15, rg = lane >> 4;
    #pragma unroll
    for (int n = 0; n < 4; ++n) {
        int gc = col0 + wc * 64 + n * 16 + cl;
        float bv = bias[gc];
        #pragma unroll
        for (int m = 0; m < 4; ++m) {
            int gr = row0 + wr * 64 + m * 16 + rg * 4;
            #pragma unroll
            for (int r2 = 0; r2 < 4; ++r2)
                C[(size_t)(gr + r2) * N + gc] = acc[m][n][r2] + bv;
        }
    }
}

// ---- phase 2: recurrence. 64 WGs (1 row each), 512 threads, zero cross-WG sync.
// Wave w owns k-eighth w AND output cols [w*64, w*64+64): h is wave-private.
// ONE barrier per step; part[] parity double-buffered.
__global__ __launch_bounds__(512, 2) void rnn_reg_kernel(
    const uint* __restrict__ Rpk,    // [131072] packed fp16 pairs
    float* __restrict__ out,         // [B][T][H]: pre -> h in place
    float* __restrict__ hlast,       // [B][H]
    const float* __restrict__ h0)    // [B][H]
{
    __shared__ uint Rlds[NLDSG * 2048];     // 112 KB
    __shared__ ushort h1[Hdim];             // 1 KB, fp16 h (wave-private regions)
    __shared__ float part[2][8][Hdim];      // 32 KB, parity double-buffered

    const int tid = threadIdx.x;
    const int row = blockIdx.x;
    const int w   = tid >> 6;               // wave = k-eighth = finalize col block
    const int l   = tid & 63;
    const int col = w * 64 + l;             // finalize column

    // register-resident R: 50 x uint4 = 200 dwords
    uint4 rr4[NREGG];
    const uint* rbase = Rpk + tid * 4;
    #pragma unroll
    for (int i = 0; i < NREGG; ++i)
        rr4[i] = *(const uint4*)(rbase + i * 2048);
    // LDS-resident R: 14 groups, dense stride-16B layout
    #pragma unroll
    for (int g = 0; g < NLDSG; ++g)
        *(uint4*)&Rlds[g * 2048 + tid * 4] =
            *(const uint4*)(rbase + (NREGG + g) * 2048);

    h1[tid] = f2h(h0[row * Hdim + tid]);
    __syncthreads();

    float* orow = out + (size_t)row * Tdim * Hdim;

    for (int t = 0; t < Tdim; ++t, orow += Hdim) {
        float pre = orow[col];                            // own col, used post-barrier
        uint hval = ((const uint*)h1)[w * 32 + (l & 31)]; // own wave's h pairs

        float a0 = 0.f, a1 = 0.f, a2 = 0.f, a3 = 0.f;
        float a4 = 0.f, a5 = 0.f, a6 = 0.f, a7 = 0.f;
        // register chunks j = 0..24
        #pragma unroll
        for (int j = 0; j < NREGG / 2; ++j) {
            uint hvi = __builtin_amdgcn_readlane(hval, j);
            uint4 rA = rr4[2 * j], rB = rr4[2 * j + 1];
            a0 = dot2acc(rA.x, hvi, a0);
            a1 = dot2acc(rA.y, hvi, a1);
            a2 = dot2acc(rA.z, hvi, a2);
            a3 = dot2acc(rA.w, hvi, a3);
            a4 = dot2acc(rB.x, hvi, a4);
            a5 = dot2acc(rB.y, hvi, a5);
            a6 = dot2acc(rB.z, hvi, a6);
            a7 = dot2acc(rB.w, hvi, a7);
        }
        // LDS chunks j = 25..31
        #pragma unroll
        for (int j = 0; j < NLDSG / 2; ++j) {
            uint hvi = __builtin_amdgcn_readlane(hval, NREGG / 2 + j);
            uint4 rA = *(const uint4*)&Rlds[(2 * j) * 2048 + tid * 4];
            uint4 rB = *(const uint4*)&Rlds[(2 * j + 1) * 2048 + tid * 4];
            a0 = dot2acc(rA.x, hvi, a0);
            a1 = dot2acc(rA.y, hvi, a1);
            a2 = dot2acc(rA.z, hvi, a2);
            a3 = dot2acc(rA.w, hvi, a3);
            a4 = dot2acc(rB.x, hvi, a4);
            a5 = dot2acc(rB.y, hvi, a5);
            a6 = dot2acc(rB.z, hvi, a6);
            a7 = dot2acc(rB.w, hvi, a7);
        }
        const int p = t & 1;
        *(f32x4*)&part[p][w][l * 8]     = (f32x4){a0, a1, a2, a3};
        *(f32x4*)&part[p][w][l * 8 + 4] = (f32x4){a4, a5, a6, a7};
        __syncthreads();                                  // the ONLY barrier

        // finalize: thread owns column col = w*64+l
        float s = pre;
        #pragma unroll
        for (int e = 0; e < 8; ++e) s += part[p][e][col];
        s = fminf(fmaxf(s, -CLIPV), CLIPV);
        float e2 = __expf(2.0f * s);
        float v = (e2 - 1.0f) * fastrcp(e2 + 1.0f);       // tanh(s)
        orow[col] = v;
        h1[col] = f2h(v);                                 // own wave's region
        if (t == Tdim - 1) hlast[row * Hdim + col] = v;
        // no second barrier: h1 is wave-private; part WAR is parity-protected
    }
}

extern "C" void kernel_launch(void* const* d_in, const int* in_sizes, int n_in,
                              void* d_out, int out_size, void* d_ws, size_t ws_size,
                              hipStream_t stream) {
    const float* x    = (const float*)d_in[0];
    const float* W    = (const float*)d_in[1];
    const float* R    = (const float*)d_in[2];
    const float* bias = (const float*)d_in[3];
    const float* h0   = (const float*)d_in[4];
    float* out = (float*)d_out;

    ushort* wth = (ushort*)d_ws;                                // 512 KB
    ushort* wtl = wth + (size_t)Idim * Hdim;                    // 512 KB
    uint* rpk   = (uint*)((char*)d_ws + (1u << 20));            // 512 KB

    transpose_w_kernel<<<(Idim * Hdim + 255) / 256, 256, 0, stream>>>(W, wth, wtl);
    pack_r_kernel<<<512, 256, 0, stream>>>(R, rpk);

    dim3 gg(Bdim * Tdim / BM, Hdim / BN);
    gemm_xw<<<gg, 256, 0, stream>>>(x, wth, wtl, bias, out, Bdim * Tdim, Hdim, Idim);

    rnn_reg_kernel<<<Bdim, 512, 0, stream>>>(
        rpk, out, out + (size_t)Bdim * Tdim * Hdim, h0);
}